// Round 15
// baseline (65.699 us; speedup 1.0000x reference)
//
#include <hip/hip_runtime.h>
#include <hip/hip_bf16.h>

#define TSEQ 2048
#define CDIM 1024
#define HDIM 64
#define NROW (8 * 2048)

typedef __attribute__((ext_vector_type(8))) short bf16x8;
typedef __attribute__((ext_vector_type(4))) float f32x4;
typedef __attribute__((ext_vector_type(4))) unsigned int u32x4;

__device__ __forceinline__ unsigned short f2bf(float f) {
    return __builtin_bit_cast(unsigned short, __float2bfloat16(f));   // HW cvt, RNE
}
__device__ __forceinline__ float bf2f(unsigned short h) {
    unsigned int u = ((unsigned int)h) << 16;
    return __builtin_bit_cast(float, u);
}
// hi/lo split; self-correcting: lo = bf16(v - hi) absorbs hi's rounding.
__device__ __forceinline__ void split2(float v, unsigned short& h, unsigned short& l) {
    __hip_bfloat16 bh = __float2bfloat16(v);
    h = __builtin_bit_cast(unsigned short, bh);
    l = f2bf(v - __bfloat162float(bh));
}
__device__ __forceinline__ f32x4 mfma16(bf16x8 a, bf16x8 b, f32x4 c) {
    return __builtin_amdgcn_mfma_f32_16x16x32_bf16(a, b, c, 0, 0, 0);
}
// async global->LDS, 16B per lane; dest must be wave-uniform-base + lane*16
__device__ __forceinline__ void gload_lds16(const unsigned short* g, unsigned short* l) {
    __builtin_amdgcn_global_load_lds(
        (const __attribute__((address_space(1))) unsigned int*)(g),
        (__attribute__((address_space(3))) unsigned int*)(l), 16, 0, 0);
}
__device__ __forceinline__ void gload_lds16f(const float* g, float* l) {
    __builtin_amdgcn_global_load_lds(
        (const __attribute__((address_space(1))) unsigned int*)(g),
        (__attribute__((address_space(3))) unsigned int*)(l), 16, 0, 0);
}

// ---------------- W prep: transpose + hi/lo split ----------------
__global__ __launch_bounds__(256) void w_prep(
    const float* __restrict__ Wk, const float* __restrict__ Wq, const float* __restrict__ Wv,
    unsigned short* __restrict__ wThi, unsigned short* __restrict__ wTlo)
{
    __shared__ float tile[64][65];
    const int mm = blockIdx.x >> 4, kt = blockIdx.x & 15;
    const float* __restrict__ W = (mm == 0) ? Wk : (mm == 1) ? Wq : Wv;
    const int t = threadIdx.x;
    #pragma unroll
    for (int s = 0; s < 4; s++) {
        const int f = t + 256 * s;
        const int r = f >> 4, cq = f & 15;
        const float4 wv = *reinterpret_cast<const float4*>(&W[(long)(kt * 64 + r) * HDIM + 4 * cq]);
        tile[4 * cq + 0][r] = wv.x; tile[4 * cq + 1][r] = wv.y;
        tile[4 * cq + 2][r] = wv.z; tile[4 * cq + 3][r] = wv.w;
    }
    __syncthreads();
    const int n = t >> 2, seg = t & 3;
    unsigned short hi[16], lo[16];
    #pragma unroll
    for (int u = 0; u < 16; u++) split2(tile[n][16 * seg + u], hi[u], lo[u]);
    const long base = (long)(mm * 64 + n) * CDIM + kt * 64 + 16 * seg;
    *reinterpret_cast<uint4*>(&wThi[base + 0]) = *reinterpret_cast<uint4*>(&hi[0]);
    *reinterpret_cast<uint4*>(&wThi[base + 8]) = *reinterpret_cast<uint4*>(&hi[8]);
    *reinterpret_cast<uint4*>(&wTlo[base + 0]) = *reinterpret_cast<uint4*>(&lo[0]);
    *reinterpret_cast<uint4*>(&wTlo[base + 8]) = *reinterpret_cast<uint4*>(&lo[8]);
}

// ---------------- proj: BM=64 BN=96 BK=32, 3-slot counted-vmcnt pipeline (T3/T4) ----------
// Grid 512 (2/CU, XCD-pinned) x 256 thr (4 waves = 2wr x 2wc; mt=2, nt=3). 60 KiB LDS =
// 3 slots x 20 KiB: [Whi 96x32][Wlo 96x32][x f32 64x32]. Stage issued 2 steps ahead
// (5 gload_lds/thread); loop does s_waitcnt vmcnt(10) + RAW s_barrier (m201/m218 pattern
// - never drain to 0 mid-loop; R8/R13's __syncthreads drained every step = m233's 72%
// 2-phase stall). Slot n%3 staged at step n-2, computed at step n, reused at step n+1's
// stage (after the trailing barrier proves all waves done reading). Swizzles (both-sides):
// W rows 64B -> gran ^ (row>>1)&3 (2-way verified); x rows 128B -> gran ^ row&7.
__global__ __launch_bounds__(256, 4) void proj_mfma(
    const float* __restrict__ x,
    const unsigned short* __restrict__ wThi, const unsigned short* __restrict__ wTlo,
    unsigned short* __restrict__ khi, unsigned short* __restrict__ klo,
    unsigned short* __restrict__ qhi, unsigned short* __restrict__ qlo,
    unsigned short* __restrict__ vt)
{
    extern __shared__ __align__(16) unsigned char smem[];   // [3][20480]
    const int t = threadIdx.x;
    const int lane = t & 63, w = t >> 6;
    const int r15 = lane & 15, g = lane >> 4;
    const int wr = w >> 1, wc = w & 1;
    const int bb8 = blockIdx.x & 7;                 // XCD pin: wg%8 == batch
    const int u = blockIdx.x >> 3;                  // 0..63
    const int jj = u >> 1, nh = u & 1;              // row-tile, N-half
    const long rowbase = (long)bb8 * TSEQ + jj * 64;

    // ---- staging sources (pre-swizzled; linear LDS dest) ----
    // W: 384 hi + 384 lo slots of 16B; slot s: row=s>>2 (0..95), gran=s&3,
    //    src gran = gran ^ ((row>>1)&3)   [64B rows: 4 granules]
    const unsigned short* wsp[3];
    #pragma unroll
    for (int q = 0; q < 3; q++) {
        const int s = t + 256 * q;
        const int lo = (s >= 384);
        const int s3 = s - 384 * lo;
        const int row = s3 >> 2, gr = s3 & 3;
        wsp[q] = (lo ? wTlo : wThi) + (long)(nh * 96 + row) * CDIM
               + ((gr ^ ((row >> 1) & 3)) << 3);
    }
    // x: 512 slots of 16B (4 f32); slot s: row=s>>3 (0..63), gran=s&7, src gran ^ row&7
    long xsrc[2];
    #pragma unroll
    for (int q = 0; q < 2; q++) {
        const int s = t + 256 * q;
        const int row = s >> 3, gr = s & 7;
        xsrc[q] = (rowbase + row) * CDIM + ((gr ^ (row & 7)) << 2);
    }

    f32x4 acc[2][3];
    #pragma unroll
    for (int mt = 0; mt < 2; mt++)
        #pragma unroll
        for (int nt = 0; nt < 3; nt++) acc[mt][nt] = (f32x4){0.f, 0.f, 0.f, 0.f};

    // 5 gload_lds per thread per stage (3 W + 2 x) -> vmcnt unit = 5
    auto stage = [&](int sl, int kc) {
        unsigned char* b = smem + sl * 20480;
        #pragma unroll
        for (int q = 0; q < 3; q++)
            gload_lds16(wsp[q] + kc, (unsigned short*)(b + (t + 256 * q) * 16));
        #pragma unroll
        for (int q = 0; q < 2; q++)
            gload_lds16f(x + xsrc[q] + kc, (float*)(b + 12288 + (t + 256 * q) * 16));
    };

    auto compute = [&](int sl) {
        const unsigned short* wb = (const unsigned short*)(smem + sl * 20480);
        const float* xb = (const float*)(smem + sl * 20480 + 12288);
        bf16x8 ah[2], al[2];
        #pragma unroll
        for (int mt = 0; mt < 2; mt++) {
            const int rx = 32 * wr + 16 * mt + r15;
            const int r7 = rx & 7;
            const f32x4 a0 = *reinterpret_cast<const f32x4*>(
                xb + rx * 32 + (((2 * g + 0) ^ r7) << 2));
            const f32x4 a1 = *reinterpret_cast<const f32x4*>(
                xb + rx * 32 + (((2 * g + 1) ^ r7) << 2));
            unsigned short h0,h1,h2,h3,h4,h5,h6,h7, l0,l1,l2,l3,l4,l5,l6,l7;
            split2(a0.x, h0, l0); split2(a0.y, h1, l1); split2(a0.z, h2, l2); split2(a0.w, h3, l3);
            split2(a1.x, h4, l4); split2(a1.y, h5, l5); split2(a1.z, h6, l6); split2(a1.w, h7, l7);
            ah[mt] = (bf16x8){(short)h0,(short)h1,(short)h2,(short)h3,(short)h4,(short)h5,(short)h6,(short)h7};
            al[mt] = (bf16x8){(short)l0,(short)l1,(short)l2,(short)l3,(short)l4,(short)l5,(short)l6,(short)l7};
        }
        #pragma unroll
        for (int nt = 0; nt < 3; nt++) {
            const int rw = (3 * wc + nt) * 16 + r15;             // 0..95, 64B rows
            const int go = ((g ^ ((rw >> 1) & 3)) << 3);         // granule swizzle
            const bf16x8 bh = *reinterpret_cast<const bf16x8*>(wb + rw * 32 + go);
            const bf16x8 bl = *reinterpret_cast<const bf16x8*>(wb + 3072 + rw * 32 + go);
            #pragma unroll
            for (int mt = 0; mt < 2; mt++) {
                acc[mt][nt] = mfma16(ah[mt], bh, acc[mt][nt]);
                acc[mt][nt] = mfma16(al[mt], bh, acc[mt][nt]);
                acc[mt][nt] = mfma16(ah[mt], bl, acc[mt][nt]);
            }
        }
    };

    // prologue: 2-deep prefetch
    stage(0, 0);
    stage(1, 32);

    #pragma unroll 1
    for (int j = 0; j < 32; ++j) {
        if (j < 30) stage((j + 2) % 3, (j + 2) * 32);
        // counted wait: chunk j landed iff outstanding <= 5 * (#stages issued after j)
        if (j < 30)      { asm volatile("s_waitcnt vmcnt(10)" ::: "memory"); }
        else if (j == 30){ asm volatile("s_waitcnt vmcnt(5)"  ::: "memory"); }
        else             { asm volatile("s_waitcnt vmcnt(0)"  ::: "memory"); }
        __builtin_amdgcn_s_barrier();           // raw: j+1/j+2 stages stay in flight
        asm volatile("" ::: "memory");
        compute(j % 3);
        asm volatile("" ::: "memory");
        __builtin_amdgcn_s_barrier();           // all waves done reading slot j%3
    }

    // epilogue: D(row = 32wr+16mt+4g+reg, col = 16*(ntg&3)+r15), ntg = 6nh+3wc+nt
    #pragma unroll
    for (int nt = 0; nt < 3; nt++) {
        const int ntg = 6 * nh + 3 * wc + nt;
        const int mat = ntg >> 2;
        const int colin = (ntg & 3) * 16 + r15;
        #pragma unroll
        for (int mt = 0; mt < 2; mt++) {
            const int rl = 32 * wr + 16 * mt + 4 * g;
            if (mat == 0) {
                #pragma unroll
                for (int reg = 0; reg < 4; reg++) {
                    unsigned short h, l;
                    split2(acc[mt][nt][reg], h, l);
                    const long idx = (rowbase + rl + reg) * HDIM + colin;
                    khi[idx] = h; klo[idx] = l;
                }
            } else if (mat == 1) {
                #pragma unroll
                for (int reg = 0; reg < 4; reg++) {
                    unsigned short h, l;
                    split2(acc[mt][nt][reg] * 32.0f, h, l);   // fold sqrt(C): exact pow2
                    const long idx = (rowbase + rl + reg) * HDIM + colin;
                    qhi[idx] = h; qlo[idx] = l;
                }
            } else {
                ushort4 pk;
                pk.x = f2bf(acc[mt][nt][0]); pk.y = f2bf(acc[mt][nt][1]);
                pk.z = f2bf(acc[mt][nt][2]); pk.w = f2bf(acc[mt][nt][3]);
                const long idx = ((long)bb8 * 64 + colin) * TSEQ + jj * 64 + rl;
                *reinterpret_cast<ushort4*>(&vt[idx]) = pk;
            }
        }
    }
}

// ---------------- flash attention: shfl-based P exchange, 3 blocks/CU (unchanged R14) ----
__global__ __launch_bounds__(256, 3) void attn_part(
    const unsigned short* __restrict__ khi, const unsigned short* __restrict__ klo,
    const unsigned short* __restrict__ qhi, const unsigned short* __restrict__ qlo,
    const unsigned short* __restrict__ vt,
    float* __restrict__ po, float* __restrict__ pm, float* __restrict__ pl, int nsplit)
{
    __shared__ __align__(16) unsigned short ldsbuf[2][3 * 4096];  // [buf][Khi|Klo|V] 8KB each
    const int t = threadIdx.x, w = t >> 6, lane = t & 63;
    const int r15 = lane & 15, g = lane >> 4;
    const int id = blockIdx.x;
    const int b = id & 7;                        // XCD pin
    const int u = id >> 3;
    const int t5 = u & 31, p = u >> 5;
    int j = (t5 & 1) ? 31 - (t5 >> 1) : (t5 >> 1);   // zigzag load balance
    if (p & 1) j = 31 - j;
    const int n = j + 1;
    const int s = (p * n) / nsplit, e = ((p + 1) * n) / nsplit;
    const int pidx = (b * 32 + j) * nsplit + p;

    if (s >= e) {   // empty split: neutral partial (block-uniform branch)
        const int rr = t >> 2, cq = (t & 3) * 16;
        if ((t & 3) == 0) { pm[pidx * 64 + rr] = -3e38f; pl[pidx * 64 + rr] = 0.f; }
        const f32x4 z = (f32x4){0.f, 0.f, 0.f, 0.f};
        float* dst = &po[((long)pidx * 64 + rr) * 64 + cq];
        #pragma unroll
        for (int q = 0; q < 4; q++) *reinterpret_cast<f32x4*>(dst + 4 * q) = z;
        return;
    }

    const int row0 = t >> 3;
    const int ce = (((t & 7) ^ (row0 & 7)) << 3);          // pre-swizzled source element col
    const long bkey = (long)b * TSEQ;
    const long vrow = ((long)b * 64 + row0) * TSEQ;
    unsigned short* const lbT = &ldsbuf[0][0];

    auto stage = [&](int cur, int kb) {
        unsigned short* lb = lbT + cur * (3 * 4096) + t * 8;
        const long kgo  = (bkey + (long)kb * 64 + row0) * HDIM + ce;
        const long kgo2 = kgo + 32 * HDIM;
        const long vgo  = vrow + (long)kb * 64 + ce;
        const long vgo2 = vgo + 32L * TSEQ;
        gload_lds16(khi + kgo,  lb);
        gload_lds16(khi + kgo2, lb + 2048);
        gload_lds16(klo + kgo,  lb + 4096);
        gload_lds16(klo + kgo2, lb + 6144);
        gload_lds16(vt  + vgo,  lb + 8192);
        gload_lds16(vt  + vgo2, lb + 10240);
    };

    const long qrow = bkey + (long)j * 64 + 16 * w + r15;
    bf16x8 Qh[2], Ql[2];
    #pragma unroll
    for (int ks = 0; ks < 2; ks++) {
        Qh[ks] = *reinterpret_cast<const bf16x8*>(&qhi[qrow * HDIM + 32 * ks + 8 * g]);
        Ql[ks] = *reinterpret_cast<const bf16x8*>(&qlo[qrow * HDIM + 32 * ks + 8 * g]);
    }

    f32x4 o[4];
    #pragma unroll
    for (int ht = 0; ht < 4; ht++) o[ht] = (f32x4){0.f, 0.f, 0.f, 0.f};
    float m = -3e38f, lsum = 0.f;
    const int sw = (r15 & 7) << 4;
    const int c0 = ((16 * g) ^ sw) >> 1;
    const int c1 = ((16 * g + 64) ^ sw) >> 1;
    const int la = 16 * ((2 * g) & 3) + r15;       // P-exchange source lanes
    const int lb_ = 16 * ((2 * g + 1) & 3) + r15;
    const int msel = g >> 1;

    stage(0, s);
    __syncthreads();

    for (int kb = s; kb < e; ++kb) {
        const int cur = (kb - s) & 1;
        if (kb + 1 < e) stage(cur ^ 1, kb + 1);
        const unsigned short* Kh = lbT + cur * (3 * 4096);
        const unsigned short* Kl = Kh + 4096;
        const unsigned short* Vb = Kh + 8192;
        const bool diag = (kb == j);

        f32x4 sc[4];
        #pragma unroll
        for (int mt = 0; mt < 4; mt++) {
            const bool valid = !diag || (mt <= w);
            f32x4 sv = valid ? (f32x4){0.f, 0.f, 0.f, 0.f}
                             : (f32x4){-1e30f, -1e30f, -1e30f, -1e30f};
            if (valid) {
                const int rb = (16 * mt + r15) * 64;
                const bf16x8 ah0 = *reinterpret_cast<const bf16x8*>(&Kh[rb + c0]);
                const bf16x8 ah1 = *reinterpret_cast<const bf16x8*>(&Kh[rb + c1]);
                const bf16x8 al0 = *reinterpret_cast<const bf16x8*>(&Kl[rb + c0]);
                const bf16x8 al1 = *reinterpret_cast<const bf16x8*>(&Kl[rb + c1]);
                sv = mfma16(ah0, Qh[0], sv);
                sv = mfma16(ah0, Ql[0], sv);
                sv = mfma16(al0, Qh[0], sv);
                sv = mfma16(ah1, Qh[1], sv);
                sv = mfma16(ah1, Ql[1], sv);
                sv = mfma16(al1, Qh[1], sv);
                if (diag && mt == w) {
                    #pragma unroll
                    for (int reg = 0; reg < 4; reg++)
                        if (4 * g + reg > r15) sv[reg] = -1e30f;
                }
            }
            sc[mt] = sv;
        }

        // defer-max online softmax (THR=8); first chunk auto-escalates (m=-3e38)
        float bml = -3e38f;
        #pragma unroll
        for (int mt = 0; mt < 4; mt++)
            bml = fmaxf(bml, fmaxf(fmaxf(sc[mt][0], sc[mt][1]), fmaxf(sc[mt][2], sc[mt][3])));
        if (!__all(bml - m <= 8.0f)) {
            float bm = fmaxf(bml, __shfl_xor(bml, 16));
            bm = fmaxf(bm, __shfl_xor(bm, 32));
            const float mnew = fmaxf(m, bm);
            const float corr = __expf(m - mnew);
            lsum *= corr;
            #pragma unroll
            for (int ht = 0; ht < 4; ht++) o[ht] *= corr;
            m = mnew;
        }
        // P = exp(S - m), packed to bf16 pairs (masked entries are -1e30 -> exp = 0)
        unsigned int pk[4][2];
        #pragma unroll
        for (int mt = 0; mt < 4; mt++) {
            const float p0 = __expf(sc[mt][0] - m);
            const float p1 = __expf(sc[mt][1] - m);
            const float p2 = __expf(sc[mt][2] - m);
            const float p3 = __expf(sc[mt][3] - m);
            lsum += (p0 + p1) + (p2 + p3);
            pk[mt][0] = (unsigned int)f2bf(p0) | ((unsigned int)f2bf(p1) << 16);
            pk[mt][1] = (unsigned int)f2bf(p2) | ((unsigned int)f2bf(p3) << 16);
        }
        // PV with shfl-exchanged P (no LDS)
        #pragma unroll
        for (int ks = 0; ks < 2; ks++) {
            const int w0a = __shfl((int)pk[2 * ks + 0][0], la);
            const int w0b = __shfl((int)pk[2 * ks + 1][0], la);
            const int w1a = __shfl((int)pk[2 * ks + 0][1], la);
            const int w1b = __shfl((int)pk[2 * ks + 1][1], la);
            const int w2a = __shfl((int)pk[2 * ks + 0][0], lb_);
            const int w2b = __shfl((int)pk[2 * ks + 1][0], lb_);
            const int w3a = __shfl((int)pk[2 * ks + 0][1], lb_);
            const int w3b = __shfl((int)pk[2 * ks + 1][1], lb_);
            const u32x4 wv = {
                (unsigned int)(msel ? w0b : w0a), (unsigned int)(msel ? w1b : w1a),
                (unsigned int)(msel ? w2b : w2a), (unsigned int)(msel ? w3b : w3a)};
            const bf16x8 pb = __builtin_bit_cast(bf16x8, wv);
            const int cc = ks ? c1 : c0;
            #pragma unroll
            for (int ht = 0; ht < 4; ht++) {
                const bf16x8 av = *reinterpret_cast<const bf16x8*>(&Vb[(16 * ht + r15) * 64 + cc]);
                o[ht] = mfma16(av, pb, o[ht]);
            }
        }
        __syncthreads();
    }

    lsum += __shfl_xor(lsum, 16);
    lsum += __shfl_xor(lsum, 32);
    if (g == 0) { pm[pidx * 64 + 16 * w + r15] = m; pl[pidx * 64 + 16 * w + r15] = lsum; }
    #pragma unroll
    for (int ht = 0; ht < 4; ht++)
        *reinterpret_cast<f32x4*>(&po[((long)pidx * 64 + 16 * w + r15) * 64 + 16 * ht + 4 * g]) = o[ht];
}

// ---------------- combine partials ----------------
__global__ __launch_bounds__(256) void attn_comb(
    const float* __restrict__ po, const float* __restrict__ pm, const float* __restrict__ pl,
    float* __restrict__ out, int nsplit)
{
    const int t = threadIdx.x;
    const int b = blockIdx.x & 7, j = blockIdx.x >> 3;   // XCD pin matches producer
    const int r = t >> 2, cq = (t & 3) * 16;
    const int base = (b * 32 + j) * nsplit;

    float M = -3e38f;
    for (int p = 0; p < nsplit; ++p) M = fmaxf(M, pm[(base + p) * 64 + r]);
    float L = 0.f;
    f32x4 acc[4];
    #pragma unroll
    for (int q = 0; q < 4; q++) acc[q] = (f32x4){0.f, 0.f, 0.f, 0.f};
    for (int p = 0; p < nsplit; ++p) {
        const float wp = __expf(pm[(base + p) * 64 + r] - M);
        L += wp * pl[(base + p) * 64 + r];
        const float* src = &po[((long)(base + p) * 64 + r) * 64 + cq];
        #pragma unroll
        for (int q = 0; q < 4; q++) acc[q] += wp * *reinterpret_cast<const f32x4*>(src + 4 * q);
    }
    const float inv = 1.0f / L;
    float* dst = &out[((long)b * TSEQ + j * 64 + r) * HDIM + cq];
    #pragma unroll
    for (int q = 0; q < 4; q++) *reinterpret_cast<f32x4*>(dst + 4 * q) = acc[q] * inv;
}

extern "C" void kernel_launch(void* const* d_in, const int* in_sizes, int n_in,
                              void* d_out, int out_size, void* d_ws, size_t ws_size,
                              hipStream_t stream) {
    const float* x  = (const float*)d_in[0];
    const float* Wk = (const float*)d_in[1];
    const float* Wq = (const float*)d_in[2];
    const float* Wv = (const float*)d_in[3];
    float* outp = (float*)d_out;

    const size_t SZ = (size_t)NROW * HDIM;
    unsigned short* ws   = (unsigned short*)d_ws;
    unsigned short* khi  = ws;
    unsigned short* klo  = ws + 1 * SZ;
    unsigned short* qhi  = ws + 2 * SZ;
    unsigned short* qlo  = ws + 3 * SZ;
    unsigned short* vt   = ws + 4 * SZ;
    unsigned short* wThi = ws + 5 * SZ;
    unsigned short* wTlo = ws + 5 * SZ + 192 * 1024;

    const size_t base_bytes = (5 * SZ + 2 * 192 * 1024) * sizeof(unsigned short); // 11,272,192
    int nsplit = 4;
    while (nsplit > 1 && base_bytes + (size_t)nsplit * 4325376 > ws_size) nsplit >>= 1;

    float* po = (float*)((char*)d_ws + base_bytes);
    float* pm = po + (size_t)256 * 64 * 64 * nsplit;
    float* pl = pm + (size_t)256 * 64 * nsplit;

    w_prep<<<48, 256, 0, stream>>>(Wk, Wq, Wv, wThi, wTlo);
    proj_mfma<<<512, 256, 61440, stream>>>(x, wThi, wTlo, khi, klo, qhi, qlo, vt);
    attn_part<<<dim3(256 * nsplit), 256, 0, stream>>>(khi, klo, qhi, qlo, vt, po, pm, pl, nsplit);
    attn_comb<<<256, 256, 0, stream>>>(po, pm, pl, outp, nsplit);
}

// Round 16
// 64.829 us; speedup vs baseline: 1.0134x; 1.0134x over previous
//
#include <hip/hip_runtime.h>
#include <hip/hip_bf16.h>

#define TSEQ 2048
#define CDIM 1024
#define HDIM 64
#define NROW (8 * 2048)

typedef __attribute__((ext_vector_type(8))) short bf16x8;
typedef __attribute__((ext_vector_type(4))) float f32x4;
typedef __attribute__((ext_vector_type(4))) unsigned int u32x4;

__device__ __forceinline__ unsigned short f2bf(float f) {
    return __builtin_bit_cast(unsigned short, __float2bfloat16(f));   // HW cvt, RNE
}
__device__ __forceinline__ float bf2f(unsigned short h) {
    unsigned int u = ((unsigned int)h) << 16;
    return __builtin_bit_cast(float, u);
}
// hi/lo split; self-correcting: lo = bf16(v - hi) absorbs hi's rounding.
__device__ __forceinline__ void split2(float v, unsigned short& h, unsigned short& l) {
    __hip_bfloat16 bh = __float2bfloat16(v);
    h = __builtin_bit_cast(unsigned short, bh);
    l = f2bf(v - __bfloat162float(bh));
}
__device__ __forceinline__ f32x4 mfma16(bf16x8 a, bf16x8 b, f32x4 c) {
    return __builtin_amdgcn_mfma_f32_16x16x32_bf16(a, b, c, 0, 0, 0);
}
// async global->LDS, 16B per lane; dest must be wave-uniform-base + lane*16
__device__ __forceinline__ void gload_lds16(const unsigned short* g, unsigned short* l) {
    __builtin_amdgcn_global_load_lds(
        (const __attribute__((address_space(1))) unsigned int*)(g),
        (__attribute__((address_space(3))) unsigned int*)(l), 16, 0, 0);
}
__device__ __forceinline__ void gload_lds16f(const float* g, float* l) {
    __builtin_amdgcn_global_load_lds(
        (const __attribute__((address_space(1))) unsigned int*)(g),
        (__attribute__((address_space(3))) unsigned int*)(l), 16, 0, 0);
}

// ---------------- W prep: transpose + hi/lo split ----------------
__global__ __launch_bounds__(256) void w_prep(
    const float* __restrict__ Wk, const float* __restrict__ Wq, const float* __restrict__ Wv,
    unsigned short* __restrict__ wThi, unsigned short* __restrict__ wTlo)
{
    __shared__ float tile[64][65];
    const int mm = blockIdx.x >> 4, kt = blockIdx.x & 15;
    const float* __restrict__ W = (mm == 0) ? Wk : (mm == 1) ? Wq : Wv;
    const int t = threadIdx.x;
    #pragma unroll
    for (int s = 0; s < 4; s++) {
        const int f = t + 256 * s;
        const int r = f >> 4, cq = f & 15;
        const float4 wv = *reinterpret_cast<const float4*>(&W[(long)(kt * 64 + r) * HDIM + 4 * cq]);
        tile[4 * cq + 0][r] = wv.x; tile[4 * cq + 1][r] = wv.y;
        tile[4 * cq + 2][r] = wv.z; tile[4 * cq + 3][r] = wv.w;
    }
    __syncthreads();
    const int n = t >> 2, seg = t & 3;
    unsigned short hi[16], lo[16];
    #pragma unroll
    for (int u = 0; u < 16; u++) split2(tile[n][16 * seg + u], hi[u], lo[u]);
    const long base = (long)(mm * 64 + n) * CDIM + kt * 64 + 16 * seg;
    *reinterpret_cast<uint4*>(&wThi[base + 0]) = *reinterpret_cast<uint4*>(&hi[0]);
    *reinterpret_cast<uint4*>(&wThi[base + 8]) = *reinterpret_cast<uint4*>(&hi[8]);
    *reinterpret_cast<uint4*>(&wTlo[base + 0]) = *reinterpret_cast<uint4*>(&lo[0]);
    *reinterpret_cast<uint4*>(&wTlo[base + 8]) = *reinterpret_cast<uint4*>(&lo[8]);
}

// ---------------- proj: BM=64 BN=96 BK=32, 3-slot pipeline, ONE barrier/step ----------
// Grid 512 (2/CU, XCD-pinned) x 256 thr (4 waves = 2wr x 2wc; mt=2, nt=3). 60 KiB LDS =
// 3 slots x 20 KiB: [Whi 96x32][Wlo 96x32][x f32 64x32]. Canonical m201/T4 step:
//   vmcnt(5)  - stage(j) retired, stage(j+1)'s 5 loads STAY IN FLIGHT (never 0 mid-loop)
//   s_barrier - slot-j writes visible to all; all waves done reading slot (j+2)%3
//               (its last reader was compute(j-1), which precedes this barrier)
//   stage(j+2) into slot (j+2)%3  - overlaps compute
//   compute(j) from slot j%3
// R15's mistake was TWO barriers/step + stage-before-wait (vmcnt(10)); this removes both.
__global__ __launch_bounds__(256, 4) void proj_mfma(
    const float* __restrict__ x,
    const unsigned short* __restrict__ wThi, const unsigned short* __restrict__ wTlo,
    unsigned short* __restrict__ khi, unsigned short* __restrict__ klo,
    unsigned short* __restrict__ qhi, unsigned short* __restrict__ qlo,
    unsigned short* __restrict__ vt)
{
    extern __shared__ __align__(16) unsigned char smem[];   // [3][20480]
    const int t = threadIdx.x;
    const int lane = t & 63, w = t >> 6;
    const int r15 = lane & 15, g = lane >> 4;
    const int wr = w >> 1, wc = w & 1;
    const int bb8 = blockIdx.x & 7;                 // XCD pin: wg%8 == batch
    const int u = blockIdx.x >> 3;                  // 0..63
    const int jj = u >> 1, nh = u & 1;              // row-tile, N-half
    const long rowbase = (long)bb8 * TSEQ + jj * 64;

    // W: 384 hi + 384 lo slots of 16B; slot s: row=s>>2 (0..95), gran=s&3,
    //    src gran = gran ^ ((row>>1)&3)   [64B rows: 4 granules]
    const unsigned short* wsp[3];
    #pragma unroll
    for (int q = 0; q < 3; q++) {
        const int s = t + 256 * q;
        const int lo = (s >= 384);
        const int s3 = s - 384 * lo;
        const int row = s3 >> 2, gr = s3 & 3;
        wsp[q] = (lo ? wTlo : wThi) + (long)(nh * 96 + row) * CDIM
               + ((gr ^ ((row >> 1) & 3)) << 3);
    }
    // x: 512 slots of 16B (4 f32); slot s: row=s>>3 (0..63), gran=s&7, src gran ^ row&7
    long xsrc[2];
    #pragma unroll
    for (int q = 0; q < 2; q++) {
        const int s = t + 256 * q;
        const int row = s >> 3, gr = s & 7;
        xsrc[q] = (rowbase + row) * CDIM + ((gr ^ (row & 7)) << 2);
    }

    f32x4 acc[2][3];
    #pragma unroll
    for (int mt = 0; mt < 2; mt++)
        #pragma unroll
        for (int nt = 0; nt < 3; nt++) acc[mt][nt] = (f32x4){0.f, 0.f, 0.f, 0.f};

    // 5 gload_lds per thread per stage (3 W + 2 x) -> vmcnt unit = 5
    auto stage = [&](int sl, int kc) {
        unsigned char* b = smem + sl * 20480;
        #pragma unroll
        for (int q = 0; q < 3; q++)
            gload_lds16(wsp[q] + kc, (unsigned short*)(b + (t + 256 * q) * 16));
        #pragma unroll
        for (int q = 0; q < 2; q++)
            gload_lds16f(x + xsrc[q] + kc, (float*)(b + 12288 + (t + 256 * q) * 16));
    };

    auto compute = [&](int sl) {
        const unsigned short* wb = (const unsigned short*)(smem + sl * 20480);
        const float* xb = (const float*)(smem + sl * 20480 + 12288);
        bf16x8 ah[2], al[2];
        #pragma unroll
        for (int mt = 0; mt < 2; mt++) {
            const int rx = 32 * wr + 16 * mt + r15;
            const int r7 = rx & 7;
            const f32x4 a0 = *reinterpret_cast<const f32x4*>(
                xb + rx * 32 + (((2 * g + 0) ^ r7) << 2));
            const f32x4 a1 = *reinterpret_cast<const f32x4*>(
                xb + rx * 32 + (((2 * g + 1) ^ r7) << 2));
            unsigned short h0,h1,h2,h3,h4,h5,h6,h7, l0,l1,l2,l3,l4,l5,l6,l7;
            split2(a0.x, h0, l0); split2(a0.y, h1, l1); split2(a0.z, h2, l2); split2(a0.w, h3, l3);
            split2(a1.x, h4, l4); split2(a1.y, h5, l5); split2(a1.z, h6, l6); split2(a1.w, h7, l7);
            ah[mt] = (bf16x8){(short)h0,(short)h1,(short)h2,(short)h3,(short)h4,(short)h5,(short)h6,(short)h7};
            al[mt] = (bf16x8){(short)l0,(short)l1,(short)l2,(short)l3,(short)l4,(short)l5,(short)l6,(short)l7};
        }
        #pragma unroll
        for (int nt = 0; nt < 3; nt++) {
            const int rw = (3 * wc + nt) * 16 + r15;             // 0..95, 64B rows
            const int go = ((g ^ ((rw >> 1) & 3)) << 3);         // granule swizzle
            const bf16x8 bh = *reinterpret_cast<const bf16x8*>(wb + rw * 32 + go);
            const bf16x8 bl = *reinterpret_cast<const bf16x8*>(wb + 3072 + rw * 32 + go);
            #pragma unroll
            for (int mt = 0; mt < 2; mt++) {
                acc[mt][nt] = mfma16(ah[mt], bh, acc[mt][nt]);
                acc[mt][nt] = mfma16(al[mt], bh, acc[mt][nt]);
                acc[mt][nt] = mfma16(ah[mt], bl, acc[mt][nt]);
            }
        }
    };

    // prologue: 2-deep prefetch
    stage(0, 0);
    stage(1, 32);

    #pragma unroll 1
    for (int j = 0; j < 32; ++j) {
        // outstanding here: stage(j) + stage(j+1) = 10 (j<31) -> vmcnt(5) retires stage(j)
        if (j < 31) { asm volatile("s_waitcnt vmcnt(5)" ::: "memory"); }
        else        { asm volatile("s_waitcnt vmcnt(0)" ::: "memory"); }
        __builtin_amdgcn_s_barrier();           // ONE barrier per step
        asm volatile("" ::: "memory");
        if (j < 30) stage((j + 2) % 3, (j + 2) * 32);   // slot free: last read was compute(j-1)
        compute(j % 3);
    }

    // epilogue: D(row = 32wr+16mt+4g+reg, col = 16*(ntg&3)+r15), ntg = 6nh+3wc+nt
    #pragma unroll
    for (int nt = 0; nt < 3; nt++) {
        const int ntg = 6 * nh + 3 * wc + nt;
        const int mat = ntg >> 2;
        const int colin = (ntg & 3) * 16 + r15;
        #pragma unroll
        for (int mt = 0; mt < 2; mt++) {
            const int rl = 32 * wr + 16 * mt + 4 * g;
            if (mat == 0) {
                #pragma unroll
                for (int reg = 0; reg < 4; reg++) {
                    unsigned short h, l;
                    split2(acc[mt][nt][reg], h, l);
                    const long idx = (rowbase + rl + reg) * HDIM + colin;
                    khi[idx] = h; klo[idx] = l;
                }
            } else if (mat == 1) {
                #pragma unroll
                for (int reg = 0; reg < 4; reg++) {
                    unsigned short h, l;
                    split2(acc[mt][nt][reg] * 32.0f, h, l);   // fold sqrt(C): exact pow2
                    const long idx = (rowbase + rl + reg) * HDIM + colin;
                    qhi[idx] = h; qlo[idx] = l;
                }
            } else {
                ushort4 pk;
                pk.x = f2bf(acc[mt][nt][0]); pk.y = f2bf(acc[mt][nt][1]);
                pk.z = f2bf(acc[mt][nt][2]); pk.w = f2bf(acc[mt][nt][3]);
                const long idx = ((long)bb8 * 64 + colin) * TSEQ + jj * 64 + rl;
                *reinterpret_cast<ushort4*>(&vt[idx]) = pk;
            }
        }
    }
}

// ---------------- flash attention: shfl-based P exchange, 3 blocks/CU (unchanged R14) ----
__global__ __launch_bounds__(256, 3) void attn_part(
    const unsigned short* __restrict__ khi, const unsigned short* __restrict__ klo,
    const unsigned short* __restrict__ qhi, const unsigned short* __restrict__ qlo,
    const unsigned short* __restrict__ vt,
    float* __restrict__ po, float* __restrict__ pm, float* __restrict__ pl, int nsplit)
{
    __shared__ __align__(16) unsigned short ldsbuf[2][3 * 4096];  // [buf][Khi|Klo|V] 8KB each
    const int t = threadIdx.x, w = t >> 6, lane = t & 63;
    const int r15 = lane & 15, g = lane >> 4;
    const int id = blockIdx.x;
    const int b = id & 7;                        // XCD pin
    const int u = id >> 3;
    const int t5 = u & 31, p = u >> 5;
    int j = (t5 & 1) ? 31 - (t5 >> 1) : (t5 >> 1);   // zigzag load balance
    if (p & 1) j = 31 - j;
    const int n = j + 1;
    const int s = (p * n) / nsplit, e = ((p + 1) * n) / nsplit;
    const int pidx = (b * 32 + j) * nsplit + p;

    if (s >= e) {   // empty split: neutral partial (block-uniform branch)
        const int rr = t >> 2, cq = (t & 3) * 16;
        if ((t & 3) == 0) { pm[pidx * 64 + rr] = -3e38f; pl[pidx * 64 + rr] = 0.f; }
        const f32x4 z = (f32x4){0.f, 0.f, 0.f, 0.f};
        float* dst = &po[((long)pidx * 64 + rr) * 64 + cq];
        #pragma unroll
        for (int q = 0; q < 4; q++) *reinterpret_cast<f32x4*>(dst + 4 * q) = z;
        return;
    }

    const int row0 = t >> 3;
    const int ce = (((t & 7) ^ (row0 & 7)) << 3);          // pre-swizzled source element col
    const long bkey = (long)b * TSEQ;
    const long vrow = ((long)b * 64 + row0) * TSEQ;
    unsigned short* const lbT = &ldsbuf[0][0];

    auto stage = [&](int cur, int kb) {
        unsigned short* lb = lbT + cur * (3 * 4096) + t * 8;
        const long kgo  = (bkey + (long)kb * 64 + row0) * HDIM + ce;
        const long kgo2 = kgo + 32 * HDIM;
        const long vgo  = vrow + (long)kb * 64 + ce;
        const long vgo2 = vgo + 32L * TSEQ;
        gload_lds16(khi + kgo,  lb);
        gload_lds16(khi + kgo2, lb + 2048);
        gload_lds16(klo + kgo,  lb + 4096);
        gload_lds16(klo + kgo2, lb + 6144);
        gload_lds16(vt  + vgo,  lb + 8192);
        gload_lds16(vt  + vgo2, lb + 10240);
    };

    const long qrow = bkey + (long)j * 64 + 16 * w + r15;
    bf16x8 Qh[2], Ql[2];
    #pragma unroll
    for (int ks = 0; ks < 2; ks++) {
        Qh[ks] = *reinterpret_cast<const bf16x8*>(&qhi[qrow * HDIM + 32 * ks + 8 * g]);
        Ql[ks] = *reinterpret_cast<const bf16x8*>(&qlo[qrow * HDIM + 32 * ks + 8 * g]);
    }

    f32x4 o[4];
    #pragma unroll
    for (int ht = 0; ht < 4; ht++) o[ht] = (f32x4){0.f, 0.f, 0.f, 0.f};
    float m = -3e38f, lsum = 0.f;
    const int sw = (r15 & 7) << 4;
    const int c0 = ((16 * g) ^ sw) >> 1;
    const int c1 = ((16 * g + 64) ^ sw) >> 1;
    const int la = 16 * ((2 * g) & 3) + r15;       // P-exchange source lanes
    const int lb_ = 16 * ((2 * g + 1) & 3) + r15;
    const int msel = g >> 1;

    stage(0, s);
    __syncthreads();

    for (int kb = s; kb < e; ++kb) {
        const int cur = (kb - s) & 1;
        if (kb + 1 < e) stage(cur ^ 1, kb + 1);
        const unsigned short* Kh = lbT + cur * (3 * 4096);
        const unsigned short* Kl = Kh + 4096;
        const unsigned short* Vb = Kh + 8192;
        const bool diag = (kb == j);

        f32x4 sc[4];
        #pragma unroll
        for (int mt = 0; mt < 4; mt++) {
            const bool valid = !diag || (mt <= w);
            f32x4 sv = valid ? (f32x4){0.f, 0.f, 0.f, 0.f}
                             : (f32x4){-1e30f, -1e30f, -1e30f, -1e30f};
            if (valid) {
                const int rb = (16 * mt + r15) * 64;
                const bf16x8 ah0 = *reinterpret_cast<const bf16x8*>(&Kh[rb + c0]);
                const bf16x8 ah1 = *reinterpret_cast<const bf16x8*>(&Kh[rb + c1]);
                const bf16x8 al0 = *reinterpret_cast<const bf16x8*>(&Kl[rb + c0]);
                const bf16x8 al1 = *reinterpret_cast<const bf16x8*>(&Kl[rb + c1]);
                sv = mfma16(ah0, Qh[0], sv);
                sv = mfma16(ah0, Ql[0], sv);
                sv = mfma16(al0, Qh[0], sv);
                sv = mfma16(ah1, Qh[1], sv);
                sv = mfma16(ah1, Ql[1], sv);
                sv = mfma16(al1, Qh[1], sv);
                if (diag && mt == w) {
                    #pragma unroll
                    for (int reg = 0; reg < 4; reg++)
                        if (4 * g + reg > r15) sv[reg] = -1e30f;
                }
            }
            sc[mt] = sv;
        }

        // defer-max online softmax (THR=8); first chunk auto-escalates (m=-3e38)
        float bml = -3e38f;
        #pragma unroll
        for (int mt = 0; mt < 4; mt++)
            bml = fmaxf(bml, fmaxf(fmaxf(sc[mt][0], sc[mt][1]), fmaxf(sc[mt][2], sc[mt][3])));
        if (!__all(bml - m <= 8.0f)) {
            float bm = fmaxf(bml, __shfl_xor(bml, 16));
            bm = fmaxf(bm, __shfl_xor(bm, 32));
            const float mnew = fmaxf(m, bm);
            const float corr = __expf(m - mnew);
            lsum *= corr;
            #pragma unroll
            for (int ht = 0; ht < 4; ht++) o[ht] *= corr;
            m = mnew;
        }
        // P = exp(S - m), packed to bf16 pairs (masked entries are -1e30 -> exp = 0)
        unsigned int pk[4][2];
        #pragma unroll
        for (int mt = 0; mt < 4; mt++) {
            const float p0 = __expf(sc[mt][0] - m);
            const float p1 = __expf(sc[mt][1] - m);
            const float p2 = __expf(sc[mt][2] - m);
            const float p3 = __expf(sc[mt][3] - m);
            lsum += (p0 + p1) + (p2 + p3);
            pk[mt][0] = (unsigned int)f2bf(p0) | ((unsigned int)f2bf(p1) << 16);
            pk[mt][1] = (unsigned int)f2bf(p2) | ((unsigned int)f2bf(p3) << 16);
        }
        // PV with shfl-exchanged P (no LDS)
        #pragma unroll
        for (int ks = 0; ks < 2; ks++) {
            const int w0a = __shfl((int)pk[2 * ks + 0][0], la);
            const int w0b = __shfl((int)pk[2 * ks + 1][0], la);
            const int w1a = __shfl((int)pk[2 * ks + 0][1], la);
            const int w1b = __shfl((int)pk[2 * ks + 1][1], la);
            const int w2a = __shfl((int)pk[2 * ks + 0][0], lb_);
            const int w2b = __shfl((int)pk[2 * ks + 1][0], lb_);
            const int w3a = __shfl((int)pk[2 * ks + 0][1], lb_);
            const int w3b = __shfl((int)pk[2 * ks + 1][1], lb_);
            const u32x4 wv = {
                (unsigned int)(msel ? w0b : w0a), (unsigned int)(msel ? w1b : w1a),
                (unsigned int)(msel ? w2b : w2a), (unsigned int)(msel ? w3b : w3a)};
            const bf16x8 pb = __builtin_bit_cast(bf16x8, wv);
            const int cc = ks ? c1 : c0;
            #pragma unroll
            for (int ht = 0; ht < 4; ht++) {
                const bf16x8 av = *reinterpret_cast<const bf16x8*>(&Vb[(16 * ht + r15) * 64 + cc]);
                o[ht] = mfma16(av, pb, o[ht]);
            }
        }
        __syncthreads();
    }

    lsum += __shfl_xor(lsum, 16);
    lsum += __shfl_xor(lsum, 32);
    if (g == 0) { pm[pidx * 64 + 16 * w + r15] = m; pl[pidx * 64 + 16 * w + r15] = lsum; }
    #pragma unroll
    for (int ht = 0; ht < 4; ht++)
        *reinterpret_cast<f32x4*>(&po[((long)pidx * 64 + 16 * w + r15) * 64 + 16 * ht + 4 * g]) = o[ht];
}

// ---------------- combine partials ----------------
__global__ __launch_bounds__(256) void attn_comb(
    const float* __restrict__ po, const float* __restrict__ pm, const float* __restrict__ pl,
    float* __restrict__ out, int nsplit)
{
    const int t = threadIdx.x;
    const int b = blockIdx.x & 7, j = blockIdx.x >> 3;   // XCD pin matches producer
    const int r = t >> 2, cq = (t & 3) * 16;
    const int base = (b * 32 + j) * nsplit;

    float M = -3e38f;
    for (int p = 0; p < nsplit; ++p) M = fmaxf(M, pm[(base + p) * 64 + r]);
    float L = 0.f;
    f32x4 acc[4];
    #pragma unroll
    for (int q = 0; q < 4; q++) acc[q] = (f32x4){0.f, 0.f, 0.f, 0.f};
    for (int p = 0; p < nsplit; ++p) {
        const float wp = __expf(pm[(base + p) * 64 + r] - M);
        L += wp * pl[(base + p) * 64 + r];
        const float* src = &po[((long)(base + p) * 64 + r) * 64 + cq];
        #pragma unroll
        for (int q = 0; q < 4; q++) acc[q] += wp * *reinterpret_cast<const f32x4*>(src + 4 * q);
    }
    const float inv = 1.0f / L;
    float* dst = &out[((long)b * TSEQ + j * 64 + r) * HDIM + cq];
    #pragma unroll
    for (int q = 0; q < 4; q++) *reinterpret_cast<f32x4*>(dst + 4 * q) = acc[q] * inv;
}

extern "C" void kernel_launch(void* const* d_in, const int* in_sizes, int n_in,
                              void* d_out, int out_size, void* d_ws, size_t ws_size,
                              hipStream_t stream) {
    const float* x  = (const float*)d_in[0];
    const float* Wk = (const float*)d_in[1];
    const float* Wq = (const float*)d_in[2];
    const float* Wv = (const float*)d_in[3];
    float* outp = (float*)d_out;

    const size_t SZ = (size_t)NROW * HDIM;
    unsigned short* ws   = (unsigned short*)d_ws;
    unsigned short* khi  = ws;
    unsigned short* klo  = ws + 1 * SZ;
    unsigned short* qhi  = ws + 2 * SZ;
    unsigned short* qlo  = ws + 3 * SZ;
    unsigned short* vt   = ws + 4 * SZ;
    unsigned short* wThi = ws + 5 * SZ;
    unsigned short* wTlo = ws + 5 * SZ + 192 * 1024;

    const size_t base_bytes = (5 * SZ + 2 * 192 * 1024) * sizeof(unsigned short); // 11,272,192
    int nsplit = 4;
    while (nsplit > 1 && base_bytes + (size_t)nsplit * 4325376 > ws_size) nsplit >>= 1;

    float* po = (float*)((char*)d_ws + base_bytes);
    float* pm = po + (size_t)256 * 64 * 64 * nsplit;
    float* pl = pm + (size_t)256 * 64 * nsplit;

    w_prep<<<48, 256, 0, stream>>>(Wk, Wq, Wv, wThi, wTlo);
    proj_mfma<<<512, 256, 61440, stream>>>(x, wThi, wTlo, khi, klo, qhi, qlo, vt);
    attn_part<<<dim3(256 * nsplit), 256, 0, stream>>>(khi, klo, qhi, qlo, vt, po, pm, pl, nsplit);
    attn_comb<<<256, 256, 0, stream>>>(po, pm, pl, outp, nsplit);
}